// Round 5
// baseline (75.634 us; speedup 1.0000x reference)
//
#include <hip/hip_runtime.h>
#include <cstdint>
#include <cstddef>

// Problem constants
#define BB 64
#define TN 4096
#define FF 128
#define SPLIT 8                  // chunks per batch -> 512 blocks, 2/CU
#define NBLK (BB * SPLIT)        // 512
#define CHUNK (TN / SPLIT)       // 512
#define KT 32                    // t-rows per staged tile
#define NKT (CHUNK / KT)         // 16 phases
#define TSTRIDE 72               // bytes per f-row in bf16 transpose buffer

#define NTILE_UP 36              // upper-triangular 16x16 tiles of 128x128
#define TILE_ELEMS 256
#define PART_FLOATS (NTILE_UP * TILE_ELEMS)   // 9216 per block partial

// d_ws layout (floats): small atomic region first (memset'd), then big arrays
#define SUM0_OFF 0
#define MEAN_OFF (SUM0_OFF + BB * FF)
#define RSTD_OFF (MEAN_OFF + BB * FF)
#define SABS_OFF (RSTD_OFF + BB * FF)
#define TRI_OFF  (SABS_OFF + 1)
#define ZERO_FLOATS (TRI_OFF + 1)
#define P_OFF    24832                        // partials: [NBLK][9216]

typedef __attribute__((ext_vector_type(8))) short bf16x8_t;
typedef __attribute__((ext_vector_type(4))) short short4_t;
typedef __attribute__((ext_vector_type(4))) float f32x4;

typedef const __attribute__((address_space(1))) uint32_t* gas_t;
typedef __attribute__((address_space(3))) uint32_t* las_t;

__device__ __constant__ int kRowBase[8] = {0, 8, 15, 21, 26, 30, 33, 35};

static __device__ __forceinline__ unsigned f2bf(float f) {
    unsigned u = __builtin_bit_cast(unsigned, f);
    return (u + 0x7FFFu + ((u >> 16) & 1u)) >> 16;   // RNE
}

// ---------------------------------------------------------------------------
// Kernel 1: async-staged bf16-MFMA syrk + fused column sums + sum|x|.
// 3-deep bufG so the phase gate is a COUNTED vmcnt(4): the 4 loads issued in
// phase p (tile p+3) stay in flight across the barrier (T3/T4 pattern).
// ---------------------------------------------------------------------------
__global__ __launch_bounds__(256, 2) void cov_kernel(const float* __restrict__ x,
                                                     float* __restrict__ ws)
{
    __shared__ __align__(16) float bufG[3][KT * FF];       // 3 x 16 KiB fp32
    __shared__ __align__(16) char  bufT[2][FF * TSTRIDE];  // 2 x 9216 B bf16^T
    __shared__ float redsa[4];

    const int b = blockIdx.x / SPLIT;
    const int s = blockIdx.x % SPLIT;
    const float* xb = x + ((size_t)b * TN + (size_t)s * CHUNK) * FF;

    const int tid  = threadIdx.x;
    const int w    = tid >> 6;     // wave 0..3
    const int lane = tid & 63;
    const int m    = lane & 15;    // MFMA frag coords
    const int h    = lane >> 4;    // 0..3
    const int f    = tid & 127;    // transpose: owned feature column
    const int th   = tid >> 7;     // 0/1: t-halves 0..15 / 16..31

    f32x4 acc0[8], acc1[4];
#pragma unroll
    for (int i = 0; i < 8; ++i) acc0[i] = (f32x4){0.f, 0.f, 0.f, 0.f};
#pragma unroll
    for (int i = 0; i < 4; ++i) acc1[i] = (f32x4){0.f, 0.f, 0.f, 0.f};

    float csum = 0.f, sabs = 0.f;

    // wave w stages rows w*8 .. w*8+7 of tile kt (4 instrs x 1 KiB each)
    auto stage = [&](int kt) {
        if (kt >= NKT) return;
        const float* g = xb + ((size_t)kt * KT + w * 8) * FF + lane * 4;
        float* l = &bufG[kt % 3][w * 8 * FF];
#pragma unroll
        for (int i = 0; i < 4; ++i)
            __builtin_amdgcn_global_load_lds((gas_t)(g + i * 2 * FF),
                                             (las_t)(l + i * 2 * FF), 16, 0, 0);
    };

    // thread owns (column f, t-half th): 16 fp32 LDS reads -> bf16 packed writes
    auto transpose = [&](int kt) {
        if (kt >= NKT) return;
        const float* gb = &bufG[kt % 3][0];
        char* tb = &bufT[kt & 1][0];
        float v[16];
#pragma unroll
        for (int i = 0; i < 16; ++i) v[i] = gb[(th * 16 + i) * FF + f];
#pragma unroll
        for (int i = 0; i < 16; ++i) { csum += v[i]; sabs += fabsf(v[i]); }
#pragma unroll
        for (int q = 0; q < 4; ++q) {
            uint2 val;
            val.x = f2bf(v[q * 4 + 0]) | (f2bf(v[q * 4 + 1]) << 16);
            val.y = f2bf(v[q * 4 + 2]) | (f2bf(v[q * 4 + 3]) << 16);
            *(uint2*)(tb + f * TSTRIDE + th * 32 + q * 8) = val;
        }
    };

    auto read_frag = [&](const char* tb, int ft) -> bf16x8_t {
        const char* p = tb + (ft * 16 + m) * TSTRIDE + h * 16;
        short4_t lo = *(const short4_t*)p;
        short4_t hi = *(const short4_t*)(p + 8);
        return (bf16x8_t){lo.x, lo.y, lo.z, lo.w, hi.x, hi.y, hi.z, hi.w};
    };

    auto domfma = [&](int k) {
        const char* tb = &bufT[k & 1][0];
        bf16x8_t a0 = read_frag(tb, w);
        bf16x8_t a1 = read_frag(tb, w + 4);
        bf16x8_t bfr[8];
#pragma unroll
        for (int n = 0; n < 8; ++n) bfr[n] = read_frag(tb, n);
#pragma unroll
        for (int n = 0; n < 8; ++n)
            acc0[n] = __builtin_amdgcn_mfma_f32_16x16x32_bf16(a0, bfr[n], acc0[n], 0, 0, 0);
#pragma unroll
        for (int n = 0; n < 4; ++n)
            acc1[n] = __builtin_amdgcn_mfma_f32_16x16x32_bf16(a1, bfr[n + 4], acc1[n], 0, 0, 0);
    };

    // ---- prologue: fill the 3-deep pipe ----
    stage(0);
    stage(1);
    stage(2);
    asm volatile("s_waitcnt vmcnt(8)" ::: "memory");       // tile 0 landed
    __builtin_amdgcn_s_barrier();
    __builtin_amdgcn_sched_barrier(0);
    transpose(0);
    asm volatile("s_waitcnt vmcnt(4) lgkmcnt(0)" ::: "memory");  // tile 1 in, T0 visible
    __builtin_amdgcn_s_barrier();
    __builtin_amdgcn_sched_barrier(0);

    // ---- main pipeline: counted gate, loads stay in flight across barrier ----
    for (int p = 0; p < NKT; ++p) {
        stage(p + 3);          // async into bufG[(p+3)%3] (no readers this phase)
        transpose(p + 1);      // bufG[(p+1)%3] -> bufT[(p+1)&1]
        domfma(p);             // bufT[p&1]
        if (p < NKT - 3) {
            // ensures tile p+2 done (needed by transpose(p+2) next phase);
            // tile p+3's 4 loads remain in flight across the barrier
            asm volatile("s_waitcnt vmcnt(4) lgkmcnt(0)" ::: "memory");
        } else {
            asm volatile("s_waitcnt vmcnt(0) lgkmcnt(0)" ::: "memory");
        }
        __builtin_amdgcn_s_barrier();
        __builtin_amdgcn_sched_barrier(0);
    }

    // ---- epilogue: plain stores of upper-tri tile partials ----
    float* Pb = ws + P_OFF + (size_t)blockIdx.x * PART_FLOATS;
#pragma unroll
    for (int n = 0; n < 8; ++n) {
        if (n >= w) {
            const int tidx = kRowBase[w] + (n - w);
#pragma unroll
            for (int q = 0; q < 4; ++q)
                Pb[tidx * TILE_ELEMS + (h * 4 + q) * 16 + m] = acc0[n][q];
        }
    }
#pragma unroll
    for (int n4 = 0; n4 < 4; ++n4) {
        if (n4 >= w) {
            const int tidx = kRowBase[w + 4] + (n4 - w);
#pragma unroll
            for (int q = 0; q < 4; ++q)
                Pb[tidx * TILE_ELEMS + (h * 4 + q) * 16 + m] = acc1[n4][q];
        }
    }

    // ---- column sums (two partial owners per f) ----
    atomicAdd(&ws[SUM0_OFF + b * FF + f], csum);

    // ---- sum |x| ----
#pragma unroll
    for (int off = 32; off > 0; off >>= 1) sabs += __shfl_down(sabs, off, 64);
    if (lane == 0) redsa[w] = sabs;
    __syncthreads();
    if (tid == 0)
        atomicAdd(&ws[SABS_OFF], redsa[0] + redsa[1] + redsa[2] + redsa[3]);
}

// ---------------------------------------------------------------------------
// Kernel 2: per (b,f) mean and 1/std; diagonal read directly from P partials.
// ---------------------------------------------------------------------------
__global__ void stats_kernel(float* __restrict__ ws)
{
    const int idx = blockIdx.x * blockDim.x + threadIdx.x;  // 0..8191
    const int b = idx >> 7, f = idx & 127;
    const float mean = ws[SUM0_OFF + idx] * (1.f / TN);
    const size_t doff = (size_t)kRowBase[f >> 4] * TILE_ELEMS + (f & 15) * 17;
    float s2d = 0.f;
#pragma unroll
    for (int s = 0; s < SPLIT; ++s)
        s2d += ws[P_OFF + ((size_t)(b * SPLIT + s)) * PART_FLOATS + doff];
    const float var = s2d * (1.f / TN) - mean * mean;
    ws[MEAN_OFF + idx] = mean;
    ws[RSTD_OFF + idx] = rsqrtf(fmaxf(var, 1e-30f));
}

// ---------------------------------------------------------------------------
// Kernel 3: corr_avg_abs + strict upper-tri masked sum (reads P directly).
// ---------------------------------------------------------------------------
__global__ __launch_bounds__(256) void corr_kernel(float* __restrict__ ws)
{
    __shared__ float red[4];
    const int p = blockIdx.x * 256 + threadIdx.x;   // 0..16383
    const int f = p >> 7, g = p & 127;

    float v = 0.f;
    if (g > f) {
        const int tidx = kRowBase[f >> 4] + ((g >> 4) - (f >> 4));
        const size_t off = (size_t)tidx * TILE_ELEMS + (f & 15) * 16 + (g & 15);
        float accum = 0.f;
        for (int b = 0; b < BB; ++b) {
            float s2 = 0.f;
#pragma unroll
            for (int s = 0; s < SPLIT; ++s)
                s2 += ws[P_OFF + ((size_t)(b * SPLIT + s)) * PART_FLOATS + off];
            const float mf = ws[MEAN_OFF + b * FF + f];
            const float mg = ws[MEAN_OFF + b * FF + g];
            const float rf = ws[RSTD_OFF + b * FF + f];
            const float rg = ws[RSTD_OFF + b * FF + g];
            accum += (s2 * (1.f / TN) - mf * mg) * rf * rg;
        }
        v = fabsf(accum * (1.f / BB));
    }

#pragma unroll
    for (int off = 32; off > 0; off >>= 1) v += __shfl_down(v, off, 64);
    const int lane = threadIdx.x & 63, wid = threadIdx.x >> 6;
    if (lane == 0) red[wid] = v;
    __syncthreads();
    if (threadIdx.x == 0)
        atomicAdd(&ws[TRI_OFF], red[0] + red[1] + red[2] + red[3]);
}

// ---------------------------------------------------------------------------
// Kernel 4: write the 3 outputs.
// ---------------------------------------------------------------------------
__global__ void final_kernel(const float* __restrict__ ws, float* __restrict__ out)
{
    const float tri  = ws[TRI_OFF];
    const float sabs = ws[SABS_OFF];
    const float n_pairs = (float)(FF * (FF - 1) / 2);   // 8128
    out[0] = tri * (0.01f / n_pairs);
    out[1] = tri;
    out[2] = sabs * (1.f / FF);
}

extern "C" void kernel_launch(void* const* d_in, const int* in_sizes, int n_in,
                              void* d_out, int out_size, void* d_ws, size_t ws_size,
                              hipStream_t stream)
{
    const float* x = (const float*)d_in[0];
    float* out = (float*)d_out;
    float* ws = (float*)d_ws;

    // zero only the atomic-accumulation region
    hipMemsetAsync(d_ws, 0, (size_t)ZERO_FLOATS * sizeof(float), stream);

    hipLaunchKernelGGL(cov_kernel,   dim3(NBLK), dim3(256), 0, stream, x, ws);
    hipLaunchKernelGGL(stats_kernel, dim3((BB * FF) / 256), dim3(256), 0, stream, ws);
    hipLaunchKernelGGL(corr_kernel,  dim3((FF * FF) / 256), dim3(256), 0, stream, ws);
    hipLaunchKernelGGL(final_kernel, dim3(1), dim3(1), 0, stream, ws, out);
}

// Round 6
// 65.078 us; speedup vs baseline: 1.1622x; 1.1622x over previous
//
#include <hip/hip_runtime.h>
#include <cstdint>
#include <cstddef>

// Problem constants
#define BB 64
#define TN 4096
#define FF 128
#define SPLIT 8                  // chunks per batch -> 512 blocks, 2/CU
#define NBLK (BB * SPLIT)        // 512
#define CHUNK (TN / SPLIT)       // 512
#define KT 32                    // t-rows per staged tile
#define NKT (CHUNK / KT)         // 16 phases
#define DEPTH 4                  // bufG depth -> 3-phase latency window
#define TSTRIDE 72               // bytes per f-row in bf16 transpose buffer

#define NTILE_UP 36              // upper-triangular 16x16 tiles of 128x128
#define TILE_ELEMS 256
#define PART_FLOATS (NTILE_UP * TILE_ELEMS)   // 9216 per block partial

// d_ws layout (floats): small atomic region first (memset'd), then big arrays
#define SUM0_OFF 0
#define MEAN_OFF (SUM0_OFF + BB * FF)
#define RSTD_OFF (MEAN_OFF + BB * FF)
#define SABS_OFF (RSTD_OFF + BB * FF)
#define TRI_OFF  (SABS_OFF + 1)
#define ZERO_FLOATS (TRI_OFF + 1)
#define R_OFF    24832                        // reduced S2 tiles: [BB][9216]
#define P_OFF    (R_OFF + BB * PART_FLOATS)   // partials: [NBLK][9216]

typedef __attribute__((ext_vector_type(8))) short bf16x8_t;
typedef __attribute__((ext_vector_type(4))) short short4_t;
typedef __attribute__((ext_vector_type(4))) float f32x4;

typedef const __attribute__((address_space(1))) uint32_t* gas_t;
typedef __attribute__((address_space(3))) uint32_t* las_t;

__device__ __constant__ int kRowBase[8] = {0, 8, 15, 21, 26, 30, 33, 35};

static __device__ __forceinline__ unsigned f2bf(float f) {
    unsigned u = __builtin_bit_cast(unsigned, f);
    return (u + 0x7FFFu + ((u >> 16) & 1u)) >> 16;   // RNE
}

#define GATE_VM(N) do { asm volatile("s_waitcnt vmcnt(" #N ")" ::: "memory"); \
                        __builtin_amdgcn_sched_barrier(0); } while (0)
#define GATE_LGKM0() do { asm volatile("s_waitcnt lgkmcnt(0)" ::: "memory"); \
                          __builtin_amdgcn_sched_barrier(0); } while (0)
#define BARRIER() do { __builtin_amdgcn_s_barrier(); \
                       __builtin_amdgcn_sched_barrier(0); } while (0)

// ---------------------------------------------------------------------------
// Kernel 1: async-staged bf16-MFMA syrk + fused column sums + sum|x|.
// 4-deep bufG: tile staged in phase p is first read in phase p+3 -> the
// vmcnt(12) gate leaves 12 loads in flight across the barrier (T3/T4).
// Two barriers per phase separate {mfma reads bufT} from {transpose writes bufT}.
// ---------------------------------------------------------------------------
__global__ __launch_bounds__(256, 2) void cov_kernel(const float* __restrict__ x,
                                                     float* __restrict__ ws)
{
    __shared__ __align__(16) float bufG[DEPTH][KT * FF];   // 64 KiB fp32
    __shared__ __align__(16) char  bufT[FF * TSTRIDE];     // 9216 B bf16^T
    __shared__ float redsa[4];

    const int b = blockIdx.x / SPLIT;
    const int s = blockIdx.x % SPLIT;
    const float* xb = x + ((size_t)b * TN + (size_t)s * CHUNK) * FF;

    const int tid  = threadIdx.x;
    const int w    = tid >> 6;     // wave 0..3
    const int lane = tid & 63;
    const int m    = lane & 15;    // MFMA frag coords
    const int h    = lane >> 4;    // 0..3
    const int f    = tid & 127;    // transpose: owned feature column
    const int th   = tid >> 7;     // 0/1: t-halves 0..15 / 16..31

    f32x4 acc0[8], acc1[4];
#pragma unroll
    for (int i = 0; i < 8; ++i) acc0[i] = (f32x4){0.f, 0.f, 0.f, 0.f};
#pragma unroll
    for (int i = 0; i < 4; ++i) acc1[i] = (f32x4){0.f, 0.f, 0.f, 0.f};

    float csum = 0.f, sabs = 0.f;

    // wave w stages rows w*8 .. w*8+7 of tile kt (4 instrs x 1 KiB each)
    auto stage = [&](int kt) {
        if (kt >= NKT) return;
        const float* g = xb + ((size_t)kt * KT + w * 8) * FF + lane * 4;
        float* l = &bufG[kt & (DEPTH - 1)][w * 8 * FF];
#pragma unroll
        for (int i = 0; i < 4; ++i)
            __builtin_amdgcn_global_load_lds((gas_t)(g + i * 2 * FF),
                                             (las_t)(l + i * 2 * FF), 16, 0, 0);
    };

    // thread owns (column f, t-half th): 16 fp32 LDS reads -> bf16 packed writes
    auto transpose = [&](int kt) {
        const float* gb = &bufG[kt & (DEPTH - 1)][0];
        float v[16];
#pragma unroll
        for (int i = 0; i < 16; ++i) v[i] = gb[(th * 16 + i) * FF + f];
#pragma unroll
        for (int i = 0; i < 16; ++i) { csum += v[i]; sabs += fabsf(v[i]); }
#pragma unroll
        for (int q = 0; q < 4; ++q) {
            uint2 val;
            val.x = f2bf(v[q * 4 + 0]) | (f2bf(v[q * 4 + 1]) << 16);
            val.y = f2bf(v[q * 4 + 2]) | (f2bf(v[q * 4 + 3]) << 16);
            *(uint2*)(bufT + f * TSTRIDE + th * 32 + q * 8) = val;
        }
    };

    auto read_frag = [&](int ft) -> bf16x8_t {
        const char* p = bufT + (ft * 16 + m) * TSTRIDE + h * 16;
        short4_t lo = *(const short4_t*)p;
        short4_t hi = *(const short4_t*)(p + 8);
        return (bf16x8_t){lo.x, lo.y, lo.z, lo.w, hi.x, hi.y, hi.z, hi.w};
    };

    auto domfma = [&]() {
        bf16x8_t a0 = read_frag(w);
        bf16x8_t a1 = read_frag(w + 4);
        bf16x8_t bfr[8];
#pragma unroll
        for (int n = 0; n < 8; ++n) bfr[n] = read_frag(n);
#pragma unroll
        for (int n = 0; n < 8; ++n)
            acc0[n] = __builtin_amdgcn_mfma_f32_16x16x32_bf16(a0, bfr[n], acc0[n], 0, 0, 0);
#pragma unroll
        for (int n = 0; n < 4; ++n)
            acc1[n] = __builtin_amdgcn_mfma_f32_16x16x32_bf16(a1, bfr[n + 4], acc1[n], 0, 0, 0);
    };

    // ---- prologue: fill the 4-deep pipe ----
    stage(0); stage(1); stage(2); stage(3);
    GATE_VM(12);                 // tile 0 landed; tiles 1-3 in flight
    BARRIER();
    transpose(0);
    GATE_LGKM0();                // bufT visible
    BARRIER();

    // ---- main pipeline ----
    for (int p = 0; p < NKT; ++p) {
        stage(p + 4);            // async into bufG[(p+4)&3] (no readers now)
        domfma();                // bufT holds tile p
        if (p + 1 < NKT) {
            // retire tile p+1 (staged 3 phases ago); newer loads stay in flight
            const int c = NKT - 2 - p;    // tiles staged after p+1 (capped 3)
            if (c >= 3)      GATE_VM(12);
            else if (c == 2) GATE_VM(8);
            else if (c == 1) GATE_VM(4);
            else             GATE_VM(0);
            BARRIER();           // all waves done reading bufT
            transpose(p + 1);    // overwrite bufT with tile p+1
            GATE_LGKM0();
        }
        BARRIER();
    }

    // ---- epilogue: plain stores of upper-tri tile partials ----
    float* Pb = ws + P_OFF + (size_t)blockIdx.x * PART_FLOATS;
#pragma unroll
    for (int n = 0; n < 8; ++n) {
        if (n >= w) {
            const int tidx = kRowBase[w] + (n - w);
#pragma unroll
            for (int q = 0; q < 4; ++q)
                Pb[tidx * TILE_ELEMS + (h * 4 + q) * 16 + m] = acc0[n][q];
        }
    }
#pragma unroll
    for (int n4 = 0; n4 < 4; ++n4) {
        if (n4 >= w) {
            const int tidx = kRowBase[w + 4] + (n4 - w);
#pragma unroll
            for (int q = 0; q < 4; ++q)
                Pb[tidx * TILE_ELEMS + (h * 4 + q) * 16 + m] = acc1[n4][q];
        }
    }

    // ---- column sums (two partial owners per f) ----
    atomicAdd(&ws[SUM0_OFF + b * FF + f], csum);

    // ---- sum |x| ----
#pragma unroll
    for (int off = 32; off > 0; off >>= 1) sabs += __shfl_down(sabs, off, 64);
    if (lane == 0) redsa[w] = sabs;
    __syncthreads();
    if (tid == 0)
        atomicAdd(&ws[SABS_OFF], redsa[0] + redsa[1] + redsa[2] + redsa[3]);
}

// ---------------------------------------------------------------------------
// Kernel 2: reduce the SPLIT per-chunk partials: R[b][e] = sum_s P[b*8+s][e]
// ---------------------------------------------------------------------------
__global__ __launch_bounds__(256) void reduce_kernel(float* __restrict__ ws)
{
    const int bb = blockIdx.x / NTILE_UP;                 // batch
    const int e  = (blockIdx.x % NTILE_UP) * 256 + threadIdx.x;
    const float* P = ws + P_OFF + (size_t)bb * SPLIT * PART_FLOATS + e;
    float acc = 0.f;
#pragma unroll
    for (int s = 0; s < SPLIT; ++s) acc += P[(size_t)s * PART_FLOATS];
    ws[R_OFF + (size_t)bb * PART_FLOATS + e] = acc;
}

// ---------------------------------------------------------------------------
// Kernel 3: per (b,f) mean and 1/std from R diagonal tiles.
// ---------------------------------------------------------------------------
__global__ void stats_kernel(float* __restrict__ ws)
{
    const int idx = blockIdx.x * blockDim.x + threadIdx.x;  // 0..8191
    const int b = idx >> 7, f = idx & 127;
    const float mean = ws[SUM0_OFF + idx] * (1.f / TN);
    const float s2d = ws[R_OFF + (size_t)b * PART_FLOATS
                         + (size_t)kRowBase[f >> 4] * TILE_ELEMS + (f & 15) * 17];
    const float var = s2d * (1.f / TN) - mean * mean;
    ws[MEAN_OFF + idx] = mean;
    ws[RSTD_OFF + idx] = rsqrtf(fmaxf(var, 1e-30f));
}

// ---------------------------------------------------------------------------
// Kernel 4: corr_avg_abs + strict upper-tri masked sum (reads compact R).
// ---------------------------------------------------------------------------
__global__ __launch_bounds__(256) void corr_kernel(float* __restrict__ ws)
{
    __shared__ float red[4];
    const int p = blockIdx.x * 256 + threadIdx.x;   // 0..16383
    const int f = p >> 7, g = p & 127;

    float v = 0.f;
    if (g > f) {
        const int tidx = kRowBase[f >> 4] + ((g >> 4) - (f >> 4));
        const size_t off = (size_t)tidx * TILE_ELEMS + (f & 15) * 16 + (g & 15);
        float accum = 0.f;
#pragma unroll 8
        for (int b = 0; b < BB; ++b) {
            const float s2 = ws[R_OFF + (size_t)b * PART_FLOATS + off];
            const float mf = ws[MEAN_OFF + b * FF + f];
            const float mg = ws[MEAN_OFF + b * FF + g];
            const float rf = ws[RSTD_OFF + b * FF + f];
            const float rg = ws[RSTD_OFF + b * FF + g];
            accum += (s2 * (1.f / TN) - mf * mg) * rf * rg;
        }
        v = fabsf(accum * (1.f / BB));
    }

#pragma unroll
    for (int off = 32; off > 0; off >>= 1) v += __shfl_down(v, off, 64);
    const int lane = threadIdx.x & 63, wid = threadIdx.x >> 6;
    if (lane == 0) red[wid] = v;
    __syncthreads();
    if (threadIdx.x == 0)
        atomicAdd(&ws[TRI_OFF], red[0] + red[1] + red[2] + red[3]);
}

// ---------------------------------------------------------------------------
// Kernel 5: write the 3 outputs.
// ---------------------------------------------------------------------------
__global__ void final_kernel(const float* __restrict__ ws, float* __restrict__ out)
{
    const float tri  = ws[TRI_OFF];
    const float sabs = ws[SABS_OFF];
    const float n_pairs = (float)(FF * (FF - 1) / 2);   // 8128
    out[0] = tri * (0.01f / n_pairs);
    out[1] = tri;
    out[2] = sabs * (1.f / FF);
}

extern "C" void kernel_launch(void* const* d_in, const int* in_sizes, int n_in,
                              void* d_out, int out_size, void* d_ws, size_t ws_size,
                              hipStream_t stream)
{
    const float* x = (const float*)d_in[0];
    float* out = (float*)d_out;
    float* ws = (float*)d_ws;

    // zero only the atomic-accumulation region
    hipMemsetAsync(d_ws, 0, (size_t)ZERO_FLOATS * sizeof(float), stream);

    hipLaunchKernelGGL(cov_kernel,    dim3(NBLK), dim3(256), 0, stream, x, ws);
    hipLaunchKernelGGL(reduce_kernel, dim3(BB * NTILE_UP), dim3(256), 0, stream, ws);
    hipLaunchKernelGGL(stats_kernel,  dim3((BB * FF) / 256), dim3(256), 0, stream, ws);
    hipLaunchKernelGGL(corr_kernel,   dim3((FF * FF) / 256), dim3(256), 0, stream, ws);
    hipLaunchKernelGGL(final_kernel,  dim3(1), dim3(1), 0, stream, ws, out);
}